// Round 1
// baseline (1527.089 us; speedup 1.0000x reference)
//
#include <hip/hip_runtime.h>

typedef __bf16 bf16_t;
typedef bf16_t bf16x8 __attribute__((ext_vector_type(8)));
typedef float floatx4 __attribute__((ext_vector_type(4)));

#define F_INq 64
#define F_OUTq 128
#define PERIODSq 12
#define XROW (F_INq * PERIODSq) /* 768 */

__device__ __forceinline__ float sigf(float x) { return 1.0f / (1.0f + __expf(-x)); }
__device__ __forceinline__ float tanhff(float x) { return 1.0f - 2.0f / (__expf(2.0f * x) + 1.0f); }

// ---------------- degree / CSR build ----------------
__global__ __launch_bounds__(256) void k_init(float* deg, int* counts, int N) {
  int i = blockIdx.x * 256 + threadIdx.x;
  if (i < N) { deg[i] = 1.0f; counts[i] = 0; }  // self-loop weight 1
}

__global__ __launch_bounds__(256) void k_accum(const int* __restrict__ ei, const float* __restrict__ ew,
                                               float* deg, int* counts, int E) {
  int e = blockIdx.x * 256 + threadIdx.x;
  if (e < E) {
    int c = ei[E + e];  // target
    atomicAdd(&deg[c], ew[e]);
    atomicAdd(&counts[c], 1);
  }
}

__global__ __launch_bounds__(256) void k_dinv(float* deg, int N) {
  int i = blockIdx.x * 256 + threadIdx.x;
  if (i < N) { float d = deg[i]; deg[i] = d > 0.0f ? rsqrtf(d) : 0.0f; }
}

__global__ __launch_bounds__(1024) void k_scan(const int* __restrict__ counts, int* __restrict__ offs,
                                               int* __restrict__ cursor, int N) {
  __shared__ int sd[1024];
  int t = threadIdx.x;
  int CH = (N + 1023) >> 10;
  int base = t * CH;
  int sum = 0;
  for (int i = 0; i < CH; ++i) { int idx = base + i; if (idx < N) sum += counts[idx]; }
  sd[t] = sum;
  __syncthreads();
  for (int off = 1; off < 1024; off <<= 1) {
    int v = (t >= off) ? sd[t - off] : 0;
    __syncthreads();
    sd[t] += v;
    __syncthreads();
  }
  int run = sd[t] - sum;  // exclusive prefix
  for (int i = 0; i < CH; ++i) {
    int idx = base + i;
    if (idx < N) { offs[idx] = run; cursor[idx] = run; run += counts[idx]; }
  }
  if (t == 1023) offs[N] = sd[1023];
}

__global__ __launch_bounds__(256) void k_scatter(const int* __restrict__ ei, const float* __restrict__ ew,
                                                 const float* __restrict__ dinv, int* cursor,
                                                 int* __restrict__ csr_src, float* __restrict__ csr_nrm, int E) {
  int e = blockIdx.x * 256 + threadIdx.x;
  if (e < E) {
    int r = ei[e], c = ei[E + e];
    int p = atomicAdd(&cursor[c], 1);
    csr_src[p] = r;
    csr_nrm[p] = dinv[r] * ew[e] * dinv[c];
  }
}

// ---------------- weight precompute: W_bigT[512][192], b_comb[512], probs[12] ----------------
__global__ __launch_bounds__(256) void k_prew(
    const float* __restrict__ Wxi, const float* __restrict__ Whi,
    const float* __restrict__ Wxf, const float* __restrict__ Whf,
    const float* __restrict__ Wxc, const float* __restrict__ Whc,
    const float* __restrict__ Wxo, const float* __restrict__ Who,
    const float* __restrict__ bxi, const float* __restrict__ bhi,
    const float* __restrict__ bxf, const float* __restrict__ bhf,
    const float* __restrict__ bxc, const float* __restrict__ bhc,
    const float* __restrict__ bxo, const float* __restrict__ bho,
    const float* __restrict__ att,
    bf16_t* __restrict__ WbT, float* __restrict__ bcomb, float* __restrict__ probs) {
  const int WT = 512 * 192;
  int gid = blockIdx.x * 256 + threadIdx.x;
  if (gid < WT) {
    int col = gid / 192, k = gid % 192;
    int g = col >> 7, j = col & 127;
    const float* Wx = g == 0 ? Wxi : g == 1 ? Wxf : g == 2 ? Wxc : Wxo;
    const float* Wh = g == 0 ? Whi : g == 1 ? Whf : g == 2 ? Whc : Who;
    float s;
    if (k < 64) {
      // W_comb[k][j] = sum_kk W_x[k][kk] * W_h_top[kk][j]
      s = 0.0f;
      for (int kk = 0; kk < 128; ++kk) s += Wx[k * 128 + kk] * Wh[kk * 128 + j];
    } else {
      // W_h_bot row (k-64): W_h[(k-64)+128][j] = W_h[k+64][j]
      s = Wh[(k + 64) * 128 + j];
    }
    WbT[(size_t)col * 192 + k] = (bf16_t)s;
  } else if (gid < WT + 512) {
    int cc = gid - WT;
    int g = cc >> 7, j = cc & 127;
    const float* bx = g == 0 ? bxi : g == 1 ? bxf : g == 2 ? bxc : bxo;
    const float* bh = g == 0 ? bhi : g == 1 ? bhf : g == 2 ? bhc : bho;
    const float* Wh = g == 0 ? Whi : g == 1 ? Whf : g == 2 ? Whc : Who;
    float s = bh[j];
    for (int kk = 0; kk < 128; ++kk) s += bx[kk] * Wh[kk * 128 + j];
    bcomb[cc] = s;
  } else if (gid == WT + 512) {
    float m = att[0];
    for (int i = 1; i < PERIODSq; ++i) m = fmaxf(m, att[i]);
    float e[PERIODSq], s = 0.0f;
    for (int i = 0; i < PERIODSq; ++i) { e[i] = __expf(att[i] - m); s += e[i]; }
    for (int i = 0; i < PERIODSq; ++i) probs[i] = e[i] / s;
  }
}

// ---------------- aggregation: Xagg[t][n][64] (bf16) = A_norm @ X, all periods at once ----------------
__global__ __launch_bounds__(256) void k_agg(const float* __restrict__ X, const int* __restrict__ csr_src,
                                             const float* __restrict__ csr_nrm, const int* __restrict__ offs,
                                             const float* __restrict__ dinv, bf16_t* __restrict__ Xagg, int N) {
  int c = blockIdx.x;
  int tid = threadIdx.x;
  int s0 = offs[c], s1 = offs[c + 1];
  const int i0 = tid, i1 = tid + 256, i2 = tid + 512;  // flat idx = f*12 + t
  float a0 = 0.f, a1 = 0.f, a2 = 0.f;
  for (int e = s0; e < s1; ++e) {
    int s = csr_src[e];
    float nr = csr_nrm[e];
    const float* xp = X + (size_t)s * XROW;
    a0 += nr * xp[i0]; a1 += nr * xp[i1]; a2 += nr * xp[i2];
  }
  float dc = dinv[c];
  float self = dc * dc;
  const float* xc = X + (size_t)c * XROW;
  a0 += self * xc[i0]; a1 += self * xc[i1]; a2 += self * xc[i2];
  __shared__ float lds[XROW];
  lds[i0] = a0; lds[i1] = a1; lds[i2] = a2;
  __syncthreads();
  for (int o = tid; o < XROW; o += 256) {
    int tt = o >> 6, f = o & 63;
    Xagg[(size_t)tt * N * 64 + (size_t)c * 64 + f] = (bf16_t)lds[f * PERIODSq + tt];
  }
}

// ---------------- fused gates GEMM + LSTM cell + attention accumulate ----------------
// Z[n,0:64]=Xagg_t[n], Z[n,64:192]=H[n];  preact = Z @ W_big + b  (M=40000,K=192,N=512)
// block: 512 threads = 8 waves, BM=32 rows.  wave w: row-tile rt=w>>2, col-tiles ct=i*4+(w&3), i=0..7
// => lane-local epilogue: tile i holds gate (i>>1), half b=(i&1).
__global__ __launch_bounds__(512) void k_gate(const bf16_t* __restrict__ Xagg_t, bf16_t* __restrict__ H,
                                              float* __restrict__ C, float* __restrict__ out,
                                              const bf16_t* __restrict__ WbT, const float* __restrict__ bcomb,
                                              const float* __restrict__ probs, int t) {
  const int n0 = blockIdx.x * 32;
  const int lane = threadIdx.x & 63;
  const int w = threadIdx.x >> 6;
  const int rt = w >> 2, wq = w & 3;
  const int q = lane >> 4, c0 = lane & 15;

  floatx4 acc[8];
#pragma unroll
  for (int i = 0; i < 8; ++i) acc[i] = (floatx4){0.f, 0.f, 0.f, 0.f};

  const int rowa = n0 + rt * 16 + c0;  // A-fragment row (m = lane&15)
#pragma unroll
  for (int ks = 0; ks < 6; ++ks) {
    bf16x8 a;
    if (ks < 2)
      a = *(const bf16x8*)(Xagg_t + (size_t)rowa * 64 + ks * 32 + q * 8);
    else
      a = *(const bf16x8*)(H + (size_t)rowa * 128 + (ks - 2) * 32 + q * 8);
#pragma unroll
    for (int i = 0; i < 8; ++i) {
      int col = (i * 4 + wq) * 16 + c0;
      bf16x8 b = *(const bf16x8*)(WbT + (size_t)col * 192 + ks * 32 + q * 8);
      acc[i] = __builtin_amdgcn_mfma_f32_16x16x32_bf16(a, b, acc[i], 0, 0, 0);
    }
  }

  const float pt = probs[t];
#pragma unroll
  for (int b = 0; b < 2; ++b) {
    int jj = b * 64 + wq * 16 + c0;
    float bI = bcomb[jj], bF = bcomb[128 + jj], bC = bcomb[256 + jj], bO = bcomb[384 + jj];
#pragma unroll
    for (int r = 0; r < 4; ++r) {
      int row = n0 + rt * 16 + q * 4 + r;
      float I = sigf(acc[0 + b][r] + bI);
      float F = sigf(acc[2 + b][r] + bF);
      float Ct = tanhff(acc[4 + b][r] + bC);
      float O = sigf(acc[6 + b][r] + bO);
      size_t idx = (size_t)row * 128 + jj;
      float Cn = F * C[idx] + I * Ct;
      C[idx] = Cn;
      float Hn = O * tanhff(Cn);
      H[idx] = (bf16_t)Hn;
      out[idx] += pt * Hn;
    }
  }
}

// ---------------- host ----------------
extern "C" void kernel_launch(void* const* d_in, const int* in_sizes, int n_in,
                              void* d_out, int out_size, void* d_ws, size_t ws_size,
                              hipStream_t stream) {
  const float* X = (const float*)d_in[0];
  const int* ei = (const int*)d_in[1];
  const float* ew = (const float*)d_in[2];
  const float* att = (const float*)d_in[3];
  const float* Wxi = (const float*)d_in[4];
  const float* bxi = (const float*)d_in[5];
  const float* Whi = (const float*)d_in[6];
  const float* bhi = (const float*)d_in[7];
  const float* Wxf = (const float*)d_in[8];
  const float* bxf = (const float*)d_in[9];
  const float* Whf = (const float*)d_in[10];
  const float* bhf = (const float*)d_in[11];
  const float* Wxc = (const float*)d_in[12];
  const float* bxc = (const float*)d_in[13];
  const float* Whc = (const float*)d_in[14];
  const float* bhc = (const float*)d_in[15];
  const float* Wxo = (const float*)d_in[16];
  const float* bxo = (const float*)d_in[17];
  const float* Who = (const float*)d_in[18];
  const float* bho = (const float*)d_in[19];
  float* out = (float*)d_out;

  const int N = in_sizes[0] / XROW;  // 40000
  const int E = in_sizes[2];         // 640000

  char* p = (char*)d_ws;
  auto carve = [&](size_t bytes) {
    char* r = p;
    p += (bytes + 255) & ~(size_t)255;
    return r;
  };
  float* deg = (float*)carve((size_t)N * 4);  // becomes dinv in-place
  int* counts = (int*)carve((size_t)N * 4);
  int* offs = (int*)carve((size_t)(N + 1) * 4);
  int* cursor = (int*)carve((size_t)(N + 1) * 4);
  int* csr_src = (int*)carve((size_t)E * 4);
  float* csr_nrm = (float*)carve((size_t)E * 4);
  bf16_t* WbT = (bf16_t*)carve((size_t)512 * 192 * 2);
  float* bcomb = (float*)carve(512 * 4);
  float* probs = (float*)carve(64);
  bf16_t* Xagg = (bf16_t*)carve((size_t)PERIODSq * N * 64 * 2);
  bf16_t* Hb = (bf16_t*)carve((size_t)N * 128 * 2);
  float* Cb = (float*)carve((size_t)N * 128 * 4);

  hipMemsetAsync(Hb, 0, (size_t)N * 128 * 2, stream);
  hipMemsetAsync(Cb, 0, (size_t)N * 128 * 4, stream);
  hipMemsetAsync(out, 0, (size_t)out_size * 4, stream);

  k_init<<<(N + 255) / 256, 256, 0, stream>>>(deg, counts, N);
  k_accum<<<(E + 255) / 256, 256, 0, stream>>>(ei, ew, deg, counts, E);
  k_dinv<<<(N + 255) / 256, 256, 0, stream>>>(deg, N);
  k_scan<<<1, 1024, 0, stream>>>(counts, offs, cursor, N);
  k_scatter<<<(E + 255) / 256, 256, 0, stream>>>(ei, ew, deg, cursor, csr_src, csr_nrm, E);
  k_prew<<<(512 * 192 + 512 + 1 + 255) / 256, 256, 0, stream>>>(
      Wxi, Whi, Wxf, Whf, Wxc, Whc, Wxo, Who,
      bxi, bhi, bxf, bhf, bxc, bhc, bxo, bho, att, WbT, bcomb, probs);
  k_agg<<<N, 256, 0, stream>>>(X, csr_src, csr_nrm, offs, deg, Xagg, N);

  for (int t = 0; t < PERIODSq; ++t) {
    k_gate<<<N / 32, 512, 0, stream>>>(Xagg + (size_t)t * N * 64, Hb, Cb, out, WbT, bcomb, probs, t);
  }
}

// Round 2
// 1054.333 us; speedup vs baseline: 1.4484x; 1.4484x over previous
//
#include <hip/hip_runtime.h>

typedef __bf16 bf16_t;
typedef bf16_t bf16x4 __attribute__((ext_vector_type(4)));
typedef bf16_t bf16x8 __attribute__((ext_vector_type(8)));
typedef float floatx4 __attribute__((ext_vector_type(4)));

#define F_INq 64
#define F_OUTq 128
#define PERIODSq 12
#define XROW (F_INq * PERIODSq) /* 768 */

__device__ __forceinline__ float sigf(float x) { return 1.0f / (1.0f + __expf(-x)); }
__device__ __forceinline__ float tanhff(float x) { return 1.0f - 2.0f / (__expf(2.0f * x) + 1.0f); }

// ---------------- degree / CSR build ----------------
__global__ __launch_bounds__(256) void k_init(float* deg, int* counts, int N) {
  int i = blockIdx.x * 256 + threadIdx.x;
  if (i < N) { deg[i] = 1.0f; counts[i] = 0; }  // self-loop weight 1
}

__global__ __launch_bounds__(256) void k_accum(const int* __restrict__ ei, const float* __restrict__ ew,
                                               float* deg, int* counts, int E) {
  int e = blockIdx.x * 256 + threadIdx.x;
  if (e < E) {
    int c = ei[E + e];  // target
    atomicAdd(&deg[c], ew[e]);
    atomicAdd(&counts[c], 1);
  }
}

__global__ __launch_bounds__(256) void k_dinv(float* deg, int N) {
  int i = blockIdx.x * 256 + threadIdx.x;
  if (i < N) { float d = deg[i]; deg[i] = d > 0.0f ? rsqrtf(d) : 0.0f; }
}

__global__ __launch_bounds__(1024) void k_scan(const int* __restrict__ counts, int* __restrict__ offs,
                                               int* __restrict__ cursor, int N) {
  __shared__ int sd[1024];
  int t = threadIdx.x;
  int CH = (N + 1023) >> 10;
  int base = t * CH;
  int sum = 0;
  for (int i = 0; i < CH; ++i) { int idx = base + i; if (idx < N) sum += counts[idx]; }
  sd[t] = sum;
  __syncthreads();
  for (int off = 1; off < 1024; off <<= 1) {
    int v = (t >= off) ? sd[t - off] : 0;
    __syncthreads();
    sd[t] += v;
    __syncthreads();
  }
  int run = sd[t] - sum;  // exclusive prefix
  for (int i = 0; i < CH; ++i) {
    int idx = base + i;
    if (idx < N) { offs[idx] = run; cursor[idx] = run; run += counts[idx]; }
  }
  if (t == 1023) offs[N] = sd[1023];
}

__global__ __launch_bounds__(256) void k_scatter(const int* __restrict__ ei, const float* __restrict__ ew,
                                                 const float* __restrict__ dinv, int* cursor,
                                                 int* __restrict__ csr_src, float* __restrict__ csr_nrm, int E) {
  int e = blockIdx.x * 256 + threadIdx.x;
  if (e < E) {
    int r = ei[e], c = ei[E + e];
    int p = atomicAdd(&cursor[c], 1);
    csr_src[p] = r;
    csr_nrm[p] = dinv[r] * ew[e] * dinv[c];
  }
}

// ---------------- weight precompute: W_bigT[512][192], b_comb[512], probs[12] ----------------
__global__ __launch_bounds__(256) void k_prew(
    const float* __restrict__ Wxi, const float* __restrict__ Whi,
    const float* __restrict__ Wxf, const float* __restrict__ Whf,
    const float* __restrict__ Wxc, const float* __restrict__ Whc,
    const float* __restrict__ Wxo, const float* __restrict__ Who,
    const float* __restrict__ bxi, const float* __restrict__ bhi,
    const float* __restrict__ bxf, const float* __restrict__ bhf,
    const float* __restrict__ bxc, const float* __restrict__ bhc,
    const float* __restrict__ bxo, const float* __restrict__ bho,
    const float* __restrict__ att,
    bf16_t* __restrict__ WbT, float* __restrict__ bcomb, float* __restrict__ probs) {
  const int WT = 512 * 192;
  int gid = blockIdx.x * 256 + threadIdx.x;
  if (gid < WT) {
    int col = gid / 192, k = gid % 192;
    int g = col >> 7, j = col & 127;
    const float* Wx = g == 0 ? Wxi : g == 1 ? Wxf : g == 2 ? Wxc : Wxo;
    const float* Wh = g == 0 ? Whi : g == 1 ? Whf : g == 2 ? Whc : Who;
    float s;
    if (k < 64) {
      s = 0.0f;
      for (int kk = 0; kk < 128; ++kk) s += Wx[k * 128 + kk] * Wh[kk * 128 + j];
    } else {
      s = Wh[(k + 64) * 128 + j];
    }
    WbT[(size_t)col * 192 + k] = (bf16_t)s;
  } else if (gid < WT + 512) {
    int cc = gid - WT;
    int g = cc >> 7, j = cc & 127;
    const float* bx = g == 0 ? bxi : g == 1 ? bxf : g == 2 ? bxc : bxo;
    const float* bh = g == 0 ? bhi : g == 1 ? bhf : g == 2 ? bhc : bho;
    const float* Wh = g == 0 ? Whi : g == 1 ? Whf : g == 2 ? Whc : Who;
    float s = bh[j];
    for (int kk = 0; kk < 128; ++kk) s += bx[kk] * Wh[kk * 128 + j];
    bcomb[cc] = s;
  } else if (gid == WT + 512) {
    float m = att[0];
    for (int i = 1; i < PERIODSq; ++i) m = fmaxf(m, att[i]);
    float e[PERIODSq], s = 0.0f;
    for (int i = 0; i < PERIODSq; ++i) { e[i] = __expf(att[i] - m); s += e[i]; }
    for (int i = 0; i < PERIODSq; ++i) probs[i] = e[i] / s;
  }
}

// ---------------- X transpose/convert: X[n][f][t] fp32 -> Xb[n][t*64+f] bf16 ----------------
__global__ __launch_bounds__(192) void k_xpose(const float* __restrict__ X, bf16_t* __restrict__ Xb) {
  __shared__ float lds[XROW];
  const int n = blockIdx.x, tid = threadIdx.x;
  const float4* Xr = (const float4*)(X + (size_t)n * XROW);
  float4 v = Xr[tid];
  lds[tid * 4 + 0] = v.x;
  lds[tid * 4 + 1] = v.y;
  lds[tid * 4 + 2] = v.z;
  lds[tid * 4 + 3] = v.w;
  __syncthreads();
  const int o = tid * 4;
  bf16x4 r;
#pragma unroll
  for (int k = 0; k < 4; ++k) {
    int oo = o + k;
    int tt = oo >> 6, f = oo & 63;
    r[k] = (bf16_t)lds[f * PERIODSq + tt];
  }
  *(bf16x4*)(Xb + (size_t)n * XROW + o) = r;
}

// ---------------- aggregation (bf16 gather): Xagg[t][n][64] = A_norm @ X ----------------
// one wave per node; row = 768 bf16 t-major; lane holds flats {4L..4L+3} of 3 chunks
__global__ __launch_bounds__(256) void k_agg2(const bf16_t* __restrict__ Xb, const int* __restrict__ csr_src,
                                              const float* __restrict__ csr_nrm, const int* __restrict__ offs,
                                              const float* __restrict__ dinv, bf16_t* __restrict__ Xagg, int N) {
  const int node = blockIdx.x * 4 + (threadIdx.x >> 6);
  const int lane = threadIdx.x & 63;
  const int s0 = offs[node], s1 = offs[node + 1];
  floatx4 a0 = {0.f, 0.f, 0.f, 0.f}, a1 = a0, a2 = a0;
  for (int e = s0; e < s1; ++e) {
    int s = csr_src[e];
    float nr = csr_nrm[e];
    const bf16x4* xp = (const bf16x4*)(Xb + (size_t)s * XROW) + lane;
    bf16x4 v0 = xp[0], v1 = xp[64], v2 = xp[128];
#pragma unroll
    for (int k = 0; k < 4; ++k) {
      a0[k] += nr * (float)v0[k];
      a1[k] += nr * (float)v1[k];
      a2[k] += nr * (float)v2[k];
    }
  }
  float dc = dinv[node];
  float self = dc * dc;
  const bf16x4* xc = (const bf16x4*)(Xb + (size_t)node * XROW) + lane;
  {
    bf16x4 v0 = xc[0], v1 = xc[64], v2 = xc[128];
#pragma unroll
    for (int k = 0; k < 4; ++k) {
      a0[k] += self * (float)v0[k];
      a1[k] += self * (float)v1[k];
      a2[k] += self * (float)v2[k];
    }
  }
  const int f4 = lane & 15, tq = lane >> 4;
  floatx4 accs[3] = {a0, a1, a2};
#pragma unroll
  for (int j = 0; j < 3; ++j) {
    int tt = tq + 4 * j;
    bf16x4 r;
#pragma unroll
    for (int k = 0; k < 4; ++k) r[k] = (bf16_t)accs[j][k];
    *(bf16x4*)(Xagg + ((size_t)tt * N + node) * 64 + f4 * 4) = r;
  }
}

// ---------------- fallback aggregation (fp32 gather, used only if ws too small) ----------------
__global__ __launch_bounds__(256) void k_agg(const float* __restrict__ X, const int* __restrict__ csr_src,
                                             const float* __restrict__ csr_nrm, const int* __restrict__ offs,
                                             const float* __restrict__ dinv, bf16_t* __restrict__ Xagg, int N) {
  int c = blockIdx.x;
  int tid = threadIdx.x;
  int s0 = offs[c], s1 = offs[c + 1];
  const int i0 = tid, i1 = tid + 256, i2 = tid + 512;
  float a0 = 0.f, a1 = 0.f, a2 = 0.f;
  for (int e = s0; e < s1; ++e) {
    int s = csr_src[e];
    float nr = csr_nrm[e];
    const float* xp = X + (size_t)s * XROW;
    a0 += nr * xp[i0]; a1 += nr * xp[i1]; a2 += nr * xp[i2];
  }
  float dc = dinv[c];
  float self = dc * dc;
  const float* xc = X + (size_t)c * XROW;
  a0 += self * xc[i0]; a1 += self * xc[i1]; a2 += self * xc[i2];
  __shared__ float lds[XROW];
  lds[i0] = a0; lds[i1] = a1; lds[i2] = a2;
  __syncthreads();
  for (int o = tid; o < XROW; o += 256) {
    int tt = o >> 6, f = o & 63;
    Xagg[(size_t)tt * N * 64 + (size_t)c * 64 + f] = (bf16_t)lds[f * PERIODSq + tt];
  }
}

// ---------------- persistent fused LSTM: all 12 steps, C/Hacc in regs, H in LDS ----------------
// block = 512 thr = 8 waves, 64 rows x 512 cols. wave w: wq=w&3 (col tiles i*4+wq, i=0..7),
// wr=w>>2 (row tiles wr*2, wr*2+1). tile i = gate*2 + half  ->  lane-local LSTM epilogue.
__global__ __launch_bounds__(512) void k_gate_all(const bf16_t* __restrict__ Xagg,
                                                  const bf16_t* __restrict__ WbT,
                                                  const float* __restrict__ bcomb,
                                                  const float* __restrict__ probs,
                                                  float* __restrict__ out, int N) {
  __shared__ bf16_t Hlds[64][136];  // +8 pad: lane-stride 68 dwords -> 2-way banks (free)
  const int tid = threadIdx.x;
  const int lane = tid & 63, w = tid >> 6;
  const int wq = w & 3, wr = w >> 2;
  const int q = lane >> 4, c0 = lane & 15;
  const int n0 = blockIdx.x * 64;

  for (int i = tid; i < 64 * 136 / 2; i += 512) ((unsigned int*)Hlds)[i] = 0u;

  float bI[2], bF[2], bC[2], bO[2];
#pragma unroll
  for (int b = 0; b < 2; ++b) {
    int jj = b * 64 + wq * 16 + c0;
    bI[b] = bcomb[jj];
    bF[b] = bcomb[128 + jj];
    bC[b] = bcomb[256 + jj];
    bO[b] = bcomb[384 + jj];
  }

  floatx4 Cst[2][2], Ha[2][2];
#pragma unroll
  for (int a = 0; a < 2; ++a)
#pragma unroll
    for (int b = 0; b < 2; ++b) {
      Cst[a][b] = (floatx4){0.f, 0.f, 0.f, 0.f};
      Ha[a][b] = (floatx4){0.f, 0.f, 0.f, 0.f};
    }

  const int r0 = (wr * 2) * 16 + c0;      // local A-row, tile 0
  const int r1 = (wr * 2 + 1) * 16 + c0;  // local A-row, tile 1
  __syncthreads();

  for (int t = 0; t < PERIODSq; ++t) {
    const bf16_t* Xt = Xagg + (size_t)t * N * 64;
    floatx4 acc[2][8];
#pragma unroll
    for (int i = 0; i < 8; ++i) {
      acc[0][i] = (floatx4){0.f, 0.f, 0.f, 0.f};
      acc[1][i] = (floatx4){0.f, 0.f, 0.f, 0.f};
    }
#pragma unroll
    for (int ks = 0; ks < 6; ++ks) {
      bf16x8 A0, A1;
      if (ks < 2) {
        A0 = *(const bf16x8*)(Xt + (size_t)(n0 + r0) * 64 + ks * 32 + q * 8);
        A1 = *(const bf16x8*)(Xt + (size_t)(n0 + r1) * 64 + ks * 32 + q * 8);
      } else {
        A0 = *(const bf16x8*)(&Hlds[r0][(ks - 2) * 32 + q * 8]);
        A1 = *(const bf16x8*)(&Hlds[r1][(ks - 2) * 32 + q * 8]);
      }
#pragma unroll
      for (int i = 0; i < 8; ++i) {
        bf16x8 B = *(const bf16x8*)(WbT + (size_t)((i * 4 + wq) * 16 + c0) * 192 + ks * 32 + q * 8);
        acc[0][i] = __builtin_amdgcn_mfma_f32_16x16x32_bf16(A0, B, acc[0][i], 0, 0, 0);
        acc[1][i] = __builtin_amdgcn_mfma_f32_16x16x32_bf16(A1, B, acc[1][i], 0, 0, 0);
      }
    }
    __syncthreads();  // all H reads done before overwrite
    const float pt = probs[t];
#pragma unroll
    for (int rtl = 0; rtl < 2; ++rtl) {
#pragma unroll
      for (int b = 0; b < 2; ++b) {
        const int jj = b * 64 + wq * 16 + c0;
#pragma unroll
        for (int r = 0; r < 4; ++r) {
          float I = sigf(acc[rtl][0 + b][r] + bI[b]);
          float F = sigf(acc[rtl][2 + b][r] + bF[b]);
          float Ct = tanhff(acc[rtl][4 + b][r] + bC[b]);
          float O = sigf(acc[rtl][6 + b][r] + bO[b]);
          float Cn = F * Cst[rtl][b][r] + I * Ct;
          Cst[rtl][b][r] = Cn;
          float Hn = O * tanhff(Cn);
          Ha[rtl][b][r] += pt * Hn;
          Hlds[(wr * 2 + rtl) * 16 + q * 4 + r][jj] = (bf16_t)Hn;
        }
      }
    }
    __syncthreads();  // H writes visible before next t's reads
  }
#pragma unroll
  for (int rtl = 0; rtl < 2; ++rtl)
#pragma unroll
    for (int b = 0; b < 2; ++b) {
      const int jj = b * 64 + wq * 16 + c0;
#pragma unroll
      for (int r = 0; r < 4; ++r) {
        int row = n0 + (wr * 2 + rtl) * 16 + q * 4 + r;
        out[(size_t)row * 128 + jj] = Ha[rtl][b][r];
      }
    }
}

// ---------------- host ----------------
extern "C" void kernel_launch(void* const* d_in, const int* in_sizes, int n_in,
                              void* d_out, int out_size, void* d_ws, size_t ws_size,
                              hipStream_t stream) {
  const float* X = (const float*)d_in[0];
  const int* ei = (const int*)d_in[1];
  const float* ew = (const float*)d_in[2];
  const float* att = (const float*)d_in[3];
  const float* Wxi = (const float*)d_in[4];
  const float* bxi = (const float*)d_in[5];
  const float* Whi = (const float*)d_in[6];
  const float* bhi = (const float*)d_in[7];
  const float* Wxf = (const float*)d_in[8];
  const float* bxf = (const float*)d_in[9];
  const float* Whf = (const float*)d_in[10];
  const float* bhf = (const float*)d_in[11];
  const float* Wxc = (const float*)d_in[12];
  const float* bxc = (const float*)d_in[13];
  const float* Whc = (const float*)d_in[14];
  const float* bhc = (const float*)d_in[15];
  const float* Wxo = (const float*)d_in[16];
  const float* bxo = (const float*)d_in[17];
  const float* Who = (const float*)d_in[18];
  const float* bho = (const float*)d_in[19];
  float* out = (float*)d_out;

  const int N = in_sizes[0] / XROW;  // 40000
  const int E = in_sizes[2];         // 640000

  char* base = (char*)d_ws;
  size_t off = 0;
  auto carve = [&](size_t bytes) {
    char* r = base + off;
    off += (bytes + 255) & ~(size_t)255;
    return (void*)r;
  };
  float* deg = (float*)carve((size_t)N * 4);  // becomes dinv in-place
  int* counts = (int*)carve((size_t)N * 4);
  int* offs = (int*)carve((size_t)(N + 1) * 4);
  int* cursor = (int*)carve((size_t)(N + 1) * 4);
  int* csr_src = (int*)carve((size_t)E * 4);
  float* csr_nrm = (float*)carve((size_t)E * 4);
  bf16_t* WbT = (bf16_t*)carve((size_t)512 * 192 * 2);
  float* bcomb = (float*)carve(512 * 4);
  float* probs = (float*)carve(64);
  bf16_t* Xagg = (bf16_t*)carve((size_t)PERIODSq * N * 64 * 2);
  size_t off_noxb = off;
  bf16_t* Xb = (bf16_t*)carve((size_t)N * XROW * 2);
  const bool use_bf16 = (off <= ws_size);  // fall back to fp32 gather if ws too small
  (void)off_noxb;

  k_init<<<(N + 255) / 256, 256, 0, stream>>>(deg, counts, N);
  k_accum<<<(E + 255) / 256, 256, 0, stream>>>(ei, ew, deg, counts, E);
  k_dinv<<<(N + 255) / 256, 256, 0, stream>>>(deg, N);
  k_scan<<<1, 1024, 0, stream>>>(counts, offs, cursor, N);
  k_scatter<<<(E + 255) / 256, 256, 0, stream>>>(ei, ew, deg, cursor, csr_src, csr_nrm, E);
  k_prew<<<(512 * 192 + 512 + 1 + 255) / 256, 256, 0, stream>>>(
      Wxi, Whi, Wxf, Whf, Wxc, Whc, Wxo, Who,
      bxi, bhi, bxf, bhf, bxc, bhc, bxo, bho, att, WbT, bcomb, probs);

  if (use_bf16) {
    k_xpose<<<N, 192, 0, stream>>>(X, Xb);
    k_agg2<<<N / 4, 256, 0, stream>>>(Xb, csr_src, csr_nrm, offs, deg, Xagg, N);
  } else {
    k_agg<<<N, 256, 0, stream>>>(X, csr_src, csr_nrm, offs, deg, Xagg, N);
  }

  k_gate_all<<<N / 64, 512, 0, stream>>>(Xagg, WbT, bcomb, probs, out, N);
}

// Round 3
// 779.287 us; speedup vs baseline: 1.9596x; 1.3529x over previous
//
#include <hip/hip_runtime.h>

typedef __bf16 bf16_t;
typedef bf16_t bf16x4 __attribute__((ext_vector_type(4)));
typedef bf16_t bf16x8 __attribute__((ext_vector_type(8)));
typedef float floatx4 __attribute__((ext_vector_type(4)));

#define F_INq 64
#define F_OUTq 128
#define PERIODSq 12
#define XROW (F_INq * PERIODSq) /* 768 */

__device__ __forceinline__ float sigf(float x) { return 1.0f / (1.0f + __expf(-x)); }
__device__ __forceinline__ float tanhff(float x) { return 1.0f - 2.0f / (__expf(2.0f * x) + 1.0f); }

// ---------------- degree / CSR build ----------------
__global__ __launch_bounds__(256) void k_init(float* deg, int* counts, int N) {
  int i = blockIdx.x * 256 + threadIdx.x;
  if (i < N) { deg[i] = 1.0f; counts[i] = 0; }  // self-loop weight 1
}

__global__ __launch_bounds__(256) void k_accum(const int* __restrict__ ei, const float* __restrict__ ew,
                                               float* deg, int* counts, int E) {
  int e = blockIdx.x * 256 + threadIdx.x;
  if (e < E) {
    int c = ei[E + e];  // target
    atomicAdd(&deg[c], ew[e]);
    atomicAdd(&counts[c], 1);
  }
}

__global__ __launch_bounds__(256) void k_dinv(float* deg, int N) {
  int i = blockIdx.x * 256 + threadIdx.x;
  if (i < N) { float d = deg[i]; deg[i] = d > 0.0f ? rsqrtf(d) : 0.0f; }
}

__global__ __launch_bounds__(1024) void k_scan(const int* __restrict__ counts, int* __restrict__ offs,
                                               int* __restrict__ cursor, int N) {
  __shared__ int sd[1024];
  int t = threadIdx.x;
  int CH = (N + 1023) >> 10;
  int base = t * CH;
  int sum = 0;
  for (int i = 0; i < CH; ++i) { int idx = base + i; if (idx < N) sum += counts[idx]; }
  sd[t] = sum;
  __syncthreads();
  for (int off = 1; off < 1024; off <<= 1) {
    int v = (t >= off) ? sd[t - off] : 0;
    __syncthreads();
    sd[t] += v;
    __syncthreads();
  }
  int run = sd[t] - sum;  // exclusive prefix
  for (int i = 0; i < CH; ++i) {
    int idx = base + i;
    if (idx < N) { offs[idx] = run; cursor[idx] = run; run += counts[idx]; }
  }
  if (t == 1023) offs[N] = sd[1023];
}

__global__ __launch_bounds__(256) void k_scatter(const int* __restrict__ ei, const float* __restrict__ ew,
                                                 const float* __restrict__ dinv, int* cursor,
                                                 int* __restrict__ csr_src, float* __restrict__ csr_nrm, int E) {
  int e = blockIdx.x * 256 + threadIdx.x;
  if (e < E) {
    int r = ei[e], c = ei[E + e];
    int p = atomicAdd(&cursor[c], 1);
    csr_src[p] = r;
    csr_nrm[p] = dinv[r] * ew[e] * dinv[c];
  }
}

// ---------------- weight precompute: W_bigT[512][192], b_comb[512], probs[12] ----------------
__global__ __launch_bounds__(256) void k_prew(
    const float* __restrict__ Wxi, const float* __restrict__ Whi,
    const float* __restrict__ Wxf, const float* __restrict__ Whf,
    const float* __restrict__ Wxc, const float* __restrict__ Whc,
    const float* __restrict__ Wxo, const float* __restrict__ Who,
    const float* __restrict__ bxi, const float* __restrict__ bhi,
    const float* __restrict__ bxf, const float* __restrict__ bhf,
    const float* __restrict__ bxc, const float* __restrict__ bhc,
    const float* __restrict__ bxo, const float* __restrict__ bho,
    const float* __restrict__ att,
    bf16_t* __restrict__ WbT, float* __restrict__ bcomb, float* __restrict__ probs) {
  const int WT = 512 * 192;
  int gid = blockIdx.x * 256 + threadIdx.x;
  if (gid < WT) {
    int col = gid / 192, k = gid % 192;
    int g = col >> 7, j = col & 127;
    const float* Wx = g == 0 ? Wxi : g == 1 ? Wxf : g == 2 ? Wxc : Wxo;
    const float* Wh = g == 0 ? Whi : g == 1 ? Whf : g == 2 ? Whc : Who;
    float s;
    if (k < 64) {
      s = 0.0f;
      for (int kk = 0; kk < 128; ++kk) s += Wx[k * 128 + kk] * Wh[kk * 128 + j];
    } else {
      s = Wh[(k + 64) * 128 + j];
    }
    WbT[(size_t)col * 192 + k] = (bf16_t)s;
  } else if (gid < WT + 512) {
    int cc = gid - WT;
    int g = cc >> 7, j = cc & 127;
    const float* bx = g == 0 ? bxi : g == 1 ? bxf : g == 2 ? bxc : bxo;
    const float* bh = g == 0 ? bhi : g == 1 ? bhf : g == 2 ? bhc : bho;
    const float* Wh = g == 0 ? Whi : g == 1 ? Whf : g == 2 ? Whc : Who;
    float s = bh[j];
    for (int kk = 0; kk < 128; ++kk) s += bx[kk] * Wh[kk * 128 + j];
    bcomb[cc] = s;
  } else if (gid == WT + 512) {
    float m = att[0];
    for (int i = 1; i < PERIODSq; ++i) m = fmaxf(m, att[i]);
    float e[PERIODSq], s = 0.0f;
    for (int i = 0; i < PERIODSq; ++i) { e[i] = __expf(att[i] - m); s += e[i]; }
    for (int i = 0; i < PERIODSq; ++i) probs[i] = e[i] / s;
  }
}

// ---------------- X transpose/convert: X[n][f][t] fp32 -> Xb[n][t*64+f] bf16 ----------------
__global__ __launch_bounds__(192) void k_xpose(const float* __restrict__ X, bf16_t* __restrict__ Xb) {
  __shared__ float lds[XROW];
  const int n = blockIdx.x, tid = threadIdx.x;
  const float4* Xr = (const float4*)(X + (size_t)n * XROW);
  float4 v = Xr[tid];
  lds[tid * 4 + 0] = v.x;
  lds[tid * 4 + 1] = v.y;
  lds[tid * 4 + 2] = v.z;
  lds[tid * 4 + 3] = v.w;
  __syncthreads();
  const int o = tid * 4;
  bf16x4 r;
#pragma unroll
  for (int k = 0; k < 4; ++k) {
    int oo = o + k;
    int tt = oo >> 6, f = oo & 63;
    r[k] = (bf16_t)lds[f * PERIODSq + tt];
  }
  *(bf16x4*)(Xb + (size_t)n * XROW + o) = r;
}

// ---------------- aggregation (bf16 gather): Xagg[t][n][64] = A_norm @ X ----------------
// one wave per node; 2-edge software pipeline to keep gathers in flight (LLC latency-bound)
__global__ __launch_bounds__(256) void k_agg2(const bf16_t* __restrict__ Xb, const int* __restrict__ csr_src,
                                              const float* __restrict__ csr_nrm, const int* __restrict__ offs,
                                              const float* __restrict__ dinv, bf16_t* __restrict__ Xagg, int N) {
  const int node = blockIdx.x * 4 + (threadIdx.x >> 6);
  const int lane = threadIdx.x & 63;
  const int s0 = offs[node], s1 = offs[node + 1];
  floatx4 a0 = {0.f, 0.f, 0.f, 0.f}, a1 = a0, a2 = a0;
  int e = s0;
  for (; e + 2 <= s1; e += 2) {
    int sA = csr_src[e], sB = csr_src[e + 1];
    float nA = csr_nrm[e], nB = csr_nrm[e + 1];
    const bf16x4* xA = (const bf16x4*)(Xb + (size_t)sA * XROW) + lane;
    const bf16x4* xB = (const bf16x4*)(Xb + (size_t)sB * XROW) + lane;
    bf16x4 vA0 = xA[0], vA1 = xA[64], vA2 = xA[128];
    bf16x4 vB0 = xB[0], vB1 = xB[64], vB2 = xB[128];
#pragma unroll
    for (int k = 0; k < 4; ++k) {
      a0[k] += nA * (float)vA0[k];
      a1[k] += nA * (float)vA1[k];
      a2[k] += nA * (float)vA2[k];
    }
#pragma unroll
    for (int k = 0; k < 4; ++k) {
      a0[k] += nB * (float)vB0[k];
      a1[k] += nB * (float)vB1[k];
      a2[k] += nB * (float)vB2[k];
    }
  }
  if (e < s1) {
    int s = csr_src[e];
    float nr = csr_nrm[e];
    const bf16x4* xp = (const bf16x4*)(Xb + (size_t)s * XROW) + lane;
    bf16x4 v0 = xp[0], v1 = xp[64], v2 = xp[128];
#pragma unroll
    for (int k = 0; k < 4; ++k) {
      a0[k] += nr * (float)v0[k];
      a1[k] += nr * (float)v1[k];
      a2[k] += nr * (float)v2[k];
    }
  }
  float dc = dinv[node];
  float self = dc * dc;
  const bf16x4* xc = (const bf16x4*)(Xb + (size_t)node * XROW) + lane;
  {
    bf16x4 v0 = xc[0], v1 = xc[64], v2 = xc[128];
#pragma unroll
    for (int k = 0; k < 4; ++k) {
      a0[k] += self * (float)v0[k];
      a1[k] += self * (float)v1[k];
      a2[k] += self * (float)v2[k];
    }
  }
  const int f4 = lane & 15, tq = lane >> 4;
  floatx4 accs[3] = {a0, a1, a2};
#pragma unroll
  for (int j = 0; j < 3; ++j) {
    int tt = tq + 4 * j;
    bf16x4 r;
#pragma unroll
    for (int k = 0; k < 4; ++k) r[k] = (bf16_t)accs[j][k];
    *(bf16x4*)(Xagg + ((size_t)tt * N + node) * 64 + f4 * 4) = r;
  }
}

// ---------------- fallback aggregation (fp32 gather, used only if ws too small) ----------------
__global__ __launch_bounds__(256) void k_agg(const float* __restrict__ X, const int* __restrict__ csr_src,
                                             const float* __restrict__ csr_nrm, const int* __restrict__ offs,
                                             const float* __restrict__ dinv, bf16_t* __restrict__ Xagg, int N) {
  int c = blockIdx.x;
  int tid = threadIdx.x;
  int s0 = offs[c], s1 = offs[c + 1];
  const int i0 = tid, i1 = tid + 256, i2 = tid + 512;
  float a0 = 0.f, a1 = 0.f, a2 = 0.f;
  for (int e = s0; e < s1; ++e) {
    int s = csr_src[e];
    float nr = csr_nrm[e];
    const float* xp = X + (size_t)s * XROW;
    a0 += nr * xp[i0]; a1 += nr * xp[i1]; a2 += nr * xp[i2];
  }
  float dc = dinv[c];
  float self = dc * dc;
  const float* xc = X + (size_t)c * XROW;
  a0 += self * xc[i0]; a1 += self * xc[i1]; a2 += self * xc[i2];
  __shared__ float lds[XROW];
  lds[i0] = a0; lds[i1] = a1; lds[i2] = a2;
  __syncthreads();
  for (int o = tid; o < XROW; o += 256) {
    int tt = o >> 6, f = o & 63;
    Xagg[(size_t)tt * N * 64 + (size_t)c * 64 + f] = (bf16_t)lds[f * PERIODSq + tt];
  }
}

// ---------------- persistent fused LSTM, W-stationary ----------------
// Block: 32 rows, 512 thr = 8 waves. Wave w owns jj-group w (jj in [w*16,w*16+16)) and holds
// W fragments for all 4 gates (A-operand, 96 VGPRs) across all 12 periods.
// Z = [Xagg_t | H] streamed via LDS as B-operand. D: node=lane&15, gate-col=q*4+r -> lane-local
// LSTM epilogue; H written back as one ds_write_b64/lane; Hacc stored as one dwordx4/lane.
#define ZP 208  // LDS row pitch (bf16): 104 dwords -> uniform 8-lane/bank-group on b128 reads
__global__ __launch_bounds__(512, 2) void k_gate_all(const bf16_t* __restrict__ Xagg,
                                                     const bf16_t* __restrict__ WbT,
                                                     const float* __restrict__ bcomb,
                                                     const float* __restrict__ probs,
                                                     float* __restrict__ out, int N) {
  __shared__ bf16_t Z[32][ZP];
  const int tid = threadIdx.x;
  const int lane = tid & 63, w = tid >> 6;
  const int q = lane >> 4, c0 = lane & 15;
  const int n0 = blockIdx.x * 32;

  // zero H region: rows 32, bytes [128,384) per row
  for (int i = tid; i < 32 * 64; i += 512) {
    int r = i >> 6, d = i & 63;
    *(unsigned int*)((char*)&Z[r][64] + d * 4) = 0u;
  }

  // stationary W fragments: col = (g*8+w)*16 + c0, k-chunk ks*32 + q*8
  bf16x8 Wf[4][6];
#pragma unroll
  for (int g = 0; g < 4; ++g) {
    const bf16_t* wp = WbT + (size_t)((g * 8 + w) * 16 + c0) * 192;
#pragma unroll
    for (int ks = 0; ks < 6; ++ks) Wf[g][ks] = *(const bf16x8*)(wp + ks * 32 + q * 8);
  }
  float bias[4][4];
#pragma unroll
  for (int g = 0; g < 4; ++g)
#pragma unroll
    for (int r = 0; r < 4; ++r) bias[g][r] = bcomb[g * 128 + w * 16 + q * 4 + r];
  float pr[PERIODSq];
#pragma unroll
  for (int t = 0; t < PERIODSq; ++t) pr[t] = probs[t];

  floatx4 Cst[2], Ha[2];
#pragma unroll
  for (int rt = 0; rt < 2; ++rt) {
    Cst[rt] = (floatx4){0.f, 0.f, 0.f, 0.f};
    Ha[rt] = (floatx4){0.f, 0.f, 0.f, 0.f};
  }

  for (int t = 0; t < PERIODSq; ++t) {
    // stage Xagg_t rows n0..n0+31 into Z[:][0:64)
    if (tid < 256) {
      int r = tid >> 3, c = tid & 7;
      const bf16_t* Xt = Xagg + (size_t)t * N * 64;
      *(bf16x8*)&Z[r][c * 8] = *(const bf16x8*)(Xt + (size_t)(n0 + r) * 64 + c * 8);
    }
    __syncthreads();
    floatx4 acc[2][4];
#pragma unroll
    for (int rt = 0; rt < 2; ++rt)
#pragma unroll
      for (int g = 0; g < 4; ++g)
        acc[rt][g] = (floatx4){bias[g][0], bias[g][1], bias[g][2], bias[g][3]};
#pragma unroll
    for (int ks = 0; ks < 6; ++ks) {
      bf16x8 B0 = *(const bf16x8*)&Z[c0][ks * 32 + q * 8];
      bf16x8 B1 = *(const bf16x8*)&Z[16 + c0][ks * 32 + q * 8];
#pragma unroll
      for (int g = 0; g < 4; ++g) {
        acc[0][g] = __builtin_amdgcn_mfma_f32_16x16x32_bf16(Wf[g][ks], B0, acc[0][g], 0, 0, 0);
        acc[1][g] = __builtin_amdgcn_mfma_f32_16x16x32_bf16(Wf[g][ks], B1, acc[1][g], 0, 0, 0);
      }
    }
    __syncthreads();  // all Z reads done before H overwrite / next X stage
    const float pt = pr[t];
#pragma unroll
    for (int rt = 0; rt < 2; ++rt) {
      bf16x4 hv;
#pragma unroll
      for (int r = 0; r < 4; ++r) {
        float I = sigf(acc[rt][0][r]);
        float F = sigf(acc[rt][1][r]);
        float Ct = tanhff(acc[rt][2][r]);
        float O = sigf(acc[rt][3][r]);
        float Cn = F * Cst[rt][r] + I * Ct;
        Cst[rt][r] = Cn;
        float Hn = O * tanhff(Cn);
        Ha[rt][r] += pt * Hn;
        hv[r] = (bf16_t)Hn;
      }
      *(bf16x4*)&Z[rt * 16 + c0][64 + w * 16 + q * 4] = hv;
    }
  }
#pragma unroll
  for (int rt = 0; rt < 2; ++rt) {
    int row = n0 + rt * 16 + c0;
    *(floatx4*)(out + (size_t)row * 128 + w * 16 + q * 4) = Ha[rt];
  }
}

// ---------------- host ----------------
extern "C" void kernel_launch(void* const* d_in, const int* in_sizes, int n_in,
                              void* d_out, int out_size, void* d_ws, size_t ws_size,
                              hipStream_t stream) {
  const float* X = (const float*)d_in[0];
  const int* ei = (const int*)d_in[1];
  const float* ew = (const float*)d_in[2];
  const float* att = (const float*)d_in[3];
  const float* Wxi = (const float*)d_in[4];
  const float* bxi = (const float*)d_in[5];
  const float* Whi = (const float*)d_in[6];
  const float* bhi = (const float*)d_in[7];
  const float* Wxf = (const float*)d_in[8];
  const float* bxf = (const float*)d_in[9];
  const float* Whf = (const float*)d_in[10];
  const float* bhf = (const float*)d_in[11];
  const float* Wxc = (const float*)d_in[12];
  const float* bxc = (const float*)d_in[13];
  const float* Whc = (const float*)d_in[14];
  const float* bhc = (const float*)d_in[15];
  const float* Wxo = (const float*)d_in[16];
  const float* bxo = (const float*)d_in[17];
  const float* Who = (const float*)d_in[18];
  const float* bho = (const float*)d_in[19];
  float* out = (float*)d_out;

  const int N = in_sizes[0] / XROW;  // 40000
  const int E = in_sizes[2];         // 640000

  char* base = (char*)d_ws;
  size_t off = 0;
  auto carve = [&](size_t bytes) {
    char* r = base + off;
    off += (bytes + 255) & ~(size_t)255;
    return (void*)r;
  };
  float* deg = (float*)carve((size_t)N * 4);  // becomes dinv in-place
  int* counts = (int*)carve((size_t)N * 4);
  int* offs = (int*)carve((size_t)(N + 1) * 4);
  int* cursor = (int*)carve((size_t)(N + 1) * 4);
  int* csr_src = (int*)carve((size_t)E * 4);
  float* csr_nrm = (float*)carve((size_t)E * 4);
  bf16_t* WbT = (bf16_t*)carve((size_t)512 * 192 * 2);
  float* bcomb = (float*)carve(512 * 4);
  float* probs = (float*)carve(64);
  bf16_t* Xagg = (bf16_t*)carve((size_t)PERIODSq * N * 64 * 2);
  bf16_t* Xb = (bf16_t*)carve((size_t)N * XROW * 2);
  const bool use_bf16 = (off <= ws_size);  // fall back to fp32 gather if ws too small

  k_init<<<(N + 255) / 256, 256, 0, stream>>>(deg, counts, N);
  k_accum<<<(E + 255) / 256, 256, 0, stream>>>(ei, ew, deg, counts, E);
  k_dinv<<<(N + 255) / 256, 256, 0, stream>>>(deg, N);
  k_scan<<<1, 1024, 0, stream>>>(counts, offs, cursor, N);
  k_scatter<<<(E + 255) / 256, 256, 0, stream>>>(ei, ew, deg, cursor, csr_src, csr_nrm, E);
  k_prew<<<(512 * 192 + 512 + 1 + 255) / 256, 256, 0, stream>>>(
      Wxi, Whi, Wxf, Whf, Wxc, Whc, Wxo, Who,
      bxi, bhi, bxf, bhf, bxc, bhc, bxo, bho, att, WbT, bcomb, probs);

  if (use_bf16) {
    k_xpose<<<N, 192, 0, stream>>>(X, Xb);
    k_agg2<<<N / 4, 256, 0, stream>>>(Xb, csr_src, csr_nrm, offs, deg, Xagg, N);
  } else {
    k_agg<<<N, 256, 0, stream>>>(X, csr_src, csr_nrm, offs, deg, Xagg, N);
  }

  k_gate_all<<<N / 32, 512, 0, stream>>>(Xagg, WbT, bcomb, probs, out, N);
}